// Round 6
// baseline (676.553 us; speedup 1.0000x reference)
//
#include <hip/hip_runtime.h>
#include <hip/hip_bf16.h>

// FraudGNN: 2-layer GraphSAGE (mean aggr) + linear head.
// N=100000, E=1600000, feat 48 -> 32 -> 16 -> 2. fp32 in/out, int edge_index.
//
// R6: delete the CSR entirely. bucket1 coarse-sorts edges by dst>>8 into
// bbuf (391 buckets x 256 nodes). bagg1/bagg2 aggregate straight from the
// bucket into LDS fp32 accumulators (ds_add_f32, ch-major layout so banks
// are indexed by random loc -> ~2-way conflicts, free), then fuse the node
// update + next projection (bagg1) / final head (bagg2) in-register.
// Self-term x@W1r computed on the fly (no r1 buffer).
//
// Algebra: mean(x[src]) @ Wl == segment_sum((x@Wl)[src]) / cnt -> project to
// OUTPUT dim first, then aggregate 32/16-wide rows.

constexpr int NN  = 100000;
constexpr int NE  = 1600000;
constexpr int NCH = (NN + 255) / 256;   // 391 node chunks
constexpr int NB  = 391;                // buckets = dst >> 8
constexpr int CAP = 4608;               // per-bucket capacity (mean 4096, ~8 sigma)
constexpr int T1  = 4096;               // edges per bucket1 block

__device__ __forceinline__ float bl(unsigned u) { return __uint_as_float(u << 16); }
__device__ __forceinline__ float bh(unsigned u) { return __uint_as_float(u & 0xffff0000u); }
__device__ __forceinline__ unsigned f2b(float x) {
    unsigned u = __float_as_uint(x);
    return (u + 0x7fffu + ((u >> 16) & 1u)) >> 16;
}
__device__ __forceinline__ unsigned pack2(float a, float b) {
    return f2b(a) | (f2b(b) << 16);
}

// ---- edge_index dtype autodetect (int64 raw vs int32 narrowed) -------------
__global__ void detect_kernel(const int* __restrict__ ei, int* __restrict__ flag)
{
    __shared__ int s_any;
    if (threadIdx.x == 0) s_any = 0;
    __syncthreads();
    int v = 0;
    for (int i = threadIdx.x; i < 2048; i += blockDim.x) v |= ei[2 * i + 1];
    if (v != 0) s_any = 1;
    __syncthreads();
    if (threadIdx.x == 0) *flag = (s_any == 0) ? 1 : 0;
}
__device__ __forceinline__ int edge_src(const int* ei, int e, int sh) {
    return ei[(size_t)e << sh];
}
__device__ __forceinline__ int edge_dst(const int* ei, int e, int sh) {
    return ei[(size_t)(NE + e) << sh];
}

// ---- P1 = X @ W1l (fp32 in, bf16 out) --------------------------------------
__global__ __launch_bounds__(256) void lin1_kernel(
    const float* __restrict__ X,
    const float* __restrict__ Wl,
    __hip_bfloat16* __restrict__ P)
{
    __shared__ float sWl[48 * 32];
    for (int i = threadIdx.x; i < 48 * 32; i += blockDim.x) sWl[i] = Wl[i];
    __syncthreads();
    int n = blockIdx.x * blockDim.x + threadIdx.x;
    if (n >= NN) return;

    float xr[48];
    const float4* xp = reinterpret_cast<const float4*>(X + (size_t)n * 48);
#pragma unroll
    for (int i = 0; i < 12; ++i) {
        float4 u = xp[i];
        xr[i*4+0] = u.x; xr[i*4+1] = u.y; xr[i*4+2] = u.z; xr[i*4+3] = u.w;
    }
    float acc[32];
#pragma unroll
    for (int j = 0; j < 32; ++j) acc[j] = 0.f;
#pragma unroll
    for (int k = 0; k < 48; ++k) {
        float xk = xr[k];
#pragma unroll
        for (int j = 0; j < 32; ++j) acc[j] += xk * sWl[k * 32 + j];
    }
    uint4* pp = reinterpret_cast<uint4*>(P + (size_t)n * 32);
#pragma unroll
    for (int i = 0; i < 4; ++i) {
        uint4 u;
        u.x = pack2(acc[i*8+0], acc[i*8+1]); u.y = pack2(acc[i*8+2], acc[i*8+3]);
        u.z = pack2(acc[i*8+4], acc[i*8+5]); u.w = pack2(acc[i*8+6], acc[i*8+7]);
        pp[i] = u;
    }
}

// ---- coarse bucket sort of edges by dst>>8 ----------------------------------
__global__ __launch_bounds__(256) void bucket1_kernel(
    const int* __restrict__ ei, const int* __restrict__ flag,
    int* __restrict__ bsize, unsigned* __restrict__ bbuf)
{
    __shared__ int hist[NB], base[NB], cur[NB];
    for (int i = threadIdx.x; i < NB; i += 256) { hist[i] = 0; cur[i] = 0; }
    __syncthreads();
    int sh = *flag;
    int e0 = blockIdx.x * T1;
    int e1 = min(e0 + T1, NE);
    for (int e = e0 + threadIdx.x; e < e1; e += 256) {
        int d = edge_dst(ei, e, sh);
        if ((unsigned)d < (unsigned)NN) atomicAdd(&hist[d >> 8], 1);
    }
    __syncthreads();
    for (int b = threadIdx.x; b < NB; b += 256) {
        int h = hist[b];
        base[b] = h ? atomicAdd(&bsize[b], h) : 0;
    }
    __syncthreads();
    for (int e = e0 + threadIdx.x; e < e1; e += 256) {
        int s = edge_src(ei, e, sh);
        int d = edge_dst(ei, e, sh);
        if ((unsigned)s >= (unsigned)NN || (unsigned)d >= (unsigned)NN) continue;
        int b = d >> 8;
        int pos = base[b] + atomicAdd(&cur[b], 1);
        if (pos < CAP)
            bbuf[(size_t)b * CAP + pos] = ((unsigned)s << 8) | (unsigned)(d & 255);
    }
}

// ---- layer 1: bucket aggregation + self-proj + relu + layer-2 projections ---
__global__ __launch_bounds__(256) void bagg1_kernel(
    const int* __restrict__ bsize, const unsigned* __restrict__ bbuf,
    const __hip_bfloat16* __restrict__ p1,     // [N,32] = x@W1l
    const float* __restrict__ X,               // [N,48]
    const float* __restrict__ W1r,             // [48,32]
    const float* __restrict__ b1,              // [32]
    const float* __restrict__ W2l,             // [32,16]
    const float* __restrict__ W2r,             // [32,16]
    __hip_bfloat16* __restrict__ P2,           // [N,16] = h@W2l
    __hip_bfloat16* __restrict__ R2)           // [N,16] = h@W2r
{
    __shared__ float acc[32 * 256];            // ch-major: acc[j*256+loc], 32 KB
    __shared__ int   ldeg[256];
    __shared__ float sW1r[48 * 32];
    __shared__ float sW2l[32 * 16], sW2r[32 * 16], sb1[32];

    int t = threadIdx.x;
    for (int i = t; i < 48 * 32; i += 256) sW1r[i] = W1r[i];
    for (int i = t; i < 32 * 16; i += 256) { sW2l[i] = W2l[i]; sW2r[i] = W2r[i]; }
    if (t < 32) sb1[t] = b1[t];
#pragma unroll
    for (int j = 0; j < 32; ++j) acc[j * 256 + t] = 0.f;
    ldeg[t] = 0;
    __syncthreads();

    int b = blockIdx.x;
    int S = min(bsize[b], CAP);
    const unsigned* bp = bbuf + (size_t)b * CAP;
    for (int i = t; i < S; i += 256) {
        unsigned pk = bp[i];
        int loc = (int)(pk & 255u);
        int s   = (int)(pk >> 8);
        const uint4* prow = reinterpret_cast<const uint4*>(p1 + (size_t)s * 32);
        uint4 u0 = prow[0], u1 = prow[1], u2 = prow[2], u3 = prow[3];
        float v[32] = { bl(u0.x), bh(u0.x), bl(u0.y), bh(u0.y),
                        bl(u0.z), bh(u0.z), bl(u0.w), bh(u0.w),
                        bl(u1.x), bh(u1.x), bl(u1.y), bh(u1.y),
                        bl(u1.z), bh(u1.z), bl(u1.w), bh(u1.w),
                        bl(u2.x), bh(u2.x), bl(u2.y), bh(u2.y),
                        bl(u2.z), bh(u2.z), bl(u2.w), bh(u2.w),
                        bl(u3.x), bh(u3.x), bl(u3.y), bh(u3.y),
                        bl(u3.z), bh(u3.z), bl(u3.w), bh(u3.w) };
        atomicAdd(&ldeg[loc], 1);
#pragma unroll
        for (int j = 0; j < 32; ++j)
            atomicAdd(&acc[j * 256 + loc], v[j]);   // ds_add_f32, bank=loc&31
    }
    __syncthreads();

    int n = (b << 8) + t;
    if (n >= NN) return;
    float inv = 1.0f / fmaxf((float)ldeg[t], 1.0f);

    // self-term x[n] @ W1r on the fly (+b1), then mean + relu
    float xr[48];
    const float4* xp = reinterpret_cast<const float4*>(X + (size_t)n * 48);
#pragma unroll
    for (int i = 0; i < 12; ++i) {
        float4 u = xp[i];
        xr[i*4+0] = u.x; xr[i*4+1] = u.y; xr[i*4+2] = u.z; xr[i*4+3] = u.w;
    }
    float h[32];
#pragma unroll
    for (int j = 0; j < 32; ++j) h[j] = sb1[j];
#pragma unroll
    for (int k = 0; k < 48; ++k) {
        float xk = xr[k];
#pragma unroll
        for (int j = 0; j < 32; ++j) h[j] += xk * sW1r[k * 32 + j];
    }
#pragma unroll
    for (int j = 0; j < 32; ++j)
        h[j] = fmaxf(h[j] + acc[j * 256 + t] * inv, 0.f);

    // layer-2 projections
    float accp[16], accr[16];
#pragma unroll
    for (int j = 0; j < 16; ++j) { accp[j] = 0.f; accr[j] = 0.f; }
#pragma unroll
    for (int k = 0; k < 32; ++k) {
        float hk = h[k];
#pragma unroll
        for (int j = 0; j < 16; ++j) {
            accp[j] += hk * sW2l[k * 16 + j];
            accr[j] += hk * sW2r[k * 16 + j];
        }
    }
    uint4* pp = reinterpret_cast<uint4*>(P2 + (size_t)n * 16);
    uint4* rr = reinterpret_cast<uint4*>(R2 + (size_t)n * 16);
#pragma unroll
    for (int i = 0; i < 2; ++i) {
        uint4 u, v;
        u.x = pack2(accp[i*8+0], accp[i*8+1]); u.y = pack2(accp[i*8+2], accp[i*8+3]);
        u.z = pack2(accp[i*8+4], accp[i*8+5]); u.w = pack2(accp[i*8+6], accp[i*8+7]);
        v.x = pack2(accr[i*8+0], accr[i*8+1]); v.y = pack2(accr[i*8+2], accr[i*8+3]);
        v.z = pack2(accr[i*8+4], accr[i*8+5]); v.w = pack2(accr[i*8+6], accr[i*8+7]);
        pp[i] = u;
        rr[i] = v;
    }
}

// ---- layer 2: bucket aggregation + relu + final head -> out -----------------
__global__ __launch_bounds__(256) void bagg2_kernel(
    const int* __restrict__ bsize, const unsigned* __restrict__ bbuf,
    const __hip_bfloat16* __restrict__ P2,     // [N,16]
    const __hip_bfloat16* __restrict__ R2,     // [N,16]
    const float* __restrict__ b2,              // [16]
    const float* __restrict__ Wlin,            // [16,2]
    const float* __restrict__ blin,            // [2]
    float* __restrict__ out)                   // [NN,2]
{
    __shared__ float acc[16 * 256];            // 16 KB
    __shared__ int   ldeg[256];
    __shared__ float sb2[16], sW[32], sbl[2];

    int t = threadIdx.x;
    if (t < 16) sb2[t] = b2[t];
    else if (t < 48) sW[t - 16] = Wlin[t - 16];
    else if (t < 50) sbl[t - 48] = blin[t - 48];
#pragma unroll
    for (int j = 0; j < 16; ++j) acc[j * 256 + t] = 0.f;
    ldeg[t] = 0;
    __syncthreads();

    int b = blockIdx.x;
    int S = min(bsize[b], CAP);
    const unsigned* bp = bbuf + (size_t)b * CAP;
    for (int i = t; i < S; i += 256) {
        unsigned pk = bp[i];
        int loc = (int)(pk & 255u);
        int s   = (int)(pk >> 8);
        const uint4* prow = reinterpret_cast<const uint4*>(P2 + (size_t)s * 16);
        uint4 u0 = prow[0], u1 = prow[1];
        float v[16] = { bl(u0.x), bh(u0.x), bl(u0.y), bh(u0.y),
                        bl(u0.z), bh(u0.z), bl(u0.w), bh(u0.w),
                        bl(u1.x), bh(u1.x), bl(u1.y), bh(u1.y),
                        bl(u1.z), bh(u1.z), bl(u1.w), bh(u1.w) };
        atomicAdd(&ldeg[loc], 1);
#pragma unroll
        for (int j = 0; j < 16; ++j)
            atomicAdd(&acc[j * 256 + loc], v[j]);
    }
    __syncthreads();

    int n = (b << 8) + t;
    if (n >= NN) return;
    float inv = 1.0f / fmaxf((float)ldeg[t], 1.0f);

    const uint4* rp = reinterpret_cast<const uint4*>(R2 + (size_t)n * 16);
    uint4 r0 = rp[0], r1v = rp[1];
    float rr[16] = { bl(r0.x), bh(r0.x), bl(r0.y), bh(r0.y),
                     bl(r0.z), bh(r0.z), bl(r0.w), bh(r0.w),
                     bl(r1v.x), bh(r1v.x), bl(r1v.y), bh(r1v.y),
                     bl(r1v.z), bh(r1v.z), bl(r1v.w), bh(r1v.w) };
    float o0 = sbl[0], o1 = sbl[1];
#pragma unroll
    for (int j = 0; j < 16; ++j) {
        float hv = fmaxf(acc[j * 256 + t] * inv + rr[j] + sb2[j], 0.f);
        o0 += hv * sW[j * 2];
        o1 += hv * sW[j * 2 + 1];
    }
    reinterpret_cast<float2*>(out)[n] = make_float2(o0, o1);
}

extern "C" void kernel_launch(void* const* d_in, const int* in_sizes, int n_in,
                              void* d_out, int out_size, void* d_ws, size_t ws_size,
                              hipStream_t stream)
{
    const float* x    = (const float*)d_in[0];
    const int*   ei   = (const int*)d_in[1];
    const float* W1l  = (const float*)d_in[2];
    const float* W1r  = (const float*)d_in[3];
    const float* b1   = (const float*)d_in[4];
    const float* W2l  = (const float*)d_in[5];
    const float* W2r  = (const float*)d_in[6];
    const float* b2   = (const float*)d_in[7];
    const float* Wlin = (const float*)d_in[8];
    const float* blin = (const float*)d_in[9];
    float* out = (float*)d_out;

    // ---- workspace layout (bytes), total ~20.02 MB ----
    // [0        , 4        ) flag
    // [64       , 1628     ) bsize  int[NB]
    // [4096     , 7212544  ) bbuf   u32[NB*CAP]   (7.21 MB, live to end)
    // [7212544  , 13612544 ) p1     bf16[N,32]    (6.4 MB)
    // [13612544 , 16812544 ) p2     bf16[N,16]    (3.2 MB)
    // [16812544 , 20012544 ) r2     bf16[N,16]    (3.2 MB)
    char* wsb = (char*)d_ws;
    int*      flag  = (int*)(wsb);
    int*      bsize = (int*)(wsb + 64);
    unsigned* bbuf  = (unsigned*)(wsb + 4096);
    __hip_bfloat16* p1 = (__hip_bfloat16*)(wsb + 7212544);
    __hip_bfloat16* p2 = (__hip_bfloat16*)(wsb + 13612544);
    __hip_bfloat16* r2 = (__hip_bfloat16*)(wsb + 16812544);

    dim3 blk(256);

    hipMemsetAsync(bsize, 0, NB * sizeof(int), stream);
    detect_kernel<<<1, blk, 0, stream>>>(ei, flag);

    lin1_kernel<<<NCH, blk, 0, stream>>>(x, W1l, p1);
    bucket1_kernel<<<(NE + T1 - 1) / T1, blk, 0, stream>>>(ei, flag, bsize, bbuf);

    bagg1_kernel<<<NB, blk, 0, stream>>>(bsize, bbuf, p1, x, W1r, b1, W2l, W2r, p2, r2);
    bagg2_kernel<<<NB, blk, 0, stream>>>(bsize, bbuf, p2, r2, b2, Wlin, blin, out);
}

// Round 7
// 216.209 us; speedup vs baseline: 3.1292x; 3.1292x over previous
//
#include <hip/hip_runtime.h>
#include <hip/hip_bf16.h>

// FraudGNN: 2-layer GraphSAGE (mean aggr) + linear head.
// N=100000, E=1600000, feat 48 -> 32 -> 16 -> 2. fp32 in/out, int edge_index.
//
// R7 = R5 structure (counting-sort CSR + per-node register gathers; R6's
// LDS-atomic bucket aggregation regressed 2.8x) with:
//  - parallel bscan (R5 had a serial 391-iter single-thread scan)
//  - node1b fused into gather1 (LDS h-exchange, 64 nodes/block)
//  - unroll-2 gather loops (2 independent row fetches in flight)
//  - bucket1: T1=2048 + register-cached (src,dst) -> edge_index read once
// ws_size proven 256 MiB -> flat layout, no aliasing.

constexpr int NN  = 100000;
constexpr int NE  = 1600000;
constexpr int NCH = (NN + 255) / 256;   // 391
constexpr int NB  = 391;                // buckets = dst >> 8
constexpr int CAP = 4608;               // per-bucket capacity (mean 4092, +8 sigma)
constexpr int T1  = 2048;               // edges per bucket1 block
constexpr int EPT = T1 / 256;           // 8 edges cached per thread

__device__ __forceinline__ float bl(unsigned u) { return __uint_as_float(u << 16); }
__device__ __forceinline__ float bh(unsigned u) { return __uint_as_float(u & 0xffff0000u); }
__device__ __forceinline__ unsigned f2b(float x) {
    unsigned u = __float_as_uint(x);
    return (u + 0x7fffu + ((u >> 16) & 1u)) >> 16;
}
__device__ __forceinline__ unsigned pack2(float a, float b) {
    return f2b(a) | (f2b(b) << 16);
}

// ---- edge_index dtype autodetect (int64 raw vs int32 narrowed) -------------
__global__ void detect_kernel(const int* __restrict__ ei, int* __restrict__ flag)
{
    __shared__ int s_any;
    if (threadIdx.x == 0) s_any = 0;
    __syncthreads();
    int v = 0;
    for (int i = threadIdx.x; i < 2048; i += blockDim.x) v |= ei[2 * i + 1];
    if (v != 0) s_any = 1;
    __syncthreads();
    if (threadIdx.x == 0) *flag = (s_any == 0) ? 1 : 0;
}
__device__ __forceinline__ int edge_src(const int* ei, int e, int sh) {
    return ei[(size_t)e << sh];
}
__device__ __forceinline__ int edge_dst(const int* ei, int e, int sh) {
    return ei[(size_t)(NE + e) << sh];
}

__device__ __forceinline__ int wave_incl_scan(int v, int lane) {
#pragma unroll
    for (int d = 1; d < 64; d <<= 1) {
        int t = __shfl_up(v, d, 64);
        if (lane >= d) v += t;
    }
    return v;
}

// ---- per-node dual linear: P = X@W1l, R = X@W1r (fp32 in, bf16 out) --------
__global__ __launch_bounds__(256) void lin2_kernel(
    const float* __restrict__ X,
    const float* __restrict__ Wl,
    const float* __restrict__ Wr,
    __hip_bfloat16* __restrict__ P, __hip_bfloat16* __restrict__ R)
{
    __shared__ float sWl[48 * 32];
    __shared__ float sWr[48 * 32];
    for (int i = threadIdx.x; i < 48 * 32; i += blockDim.x) {
        sWl[i] = Wl[i];
        sWr[i] = Wr[i];
    }
    __syncthreads();
    int n = blockIdx.x * blockDim.x + threadIdx.x;
    if (n >= NN) return;

    float xr[48];
    const float4* xp = reinterpret_cast<const float4*>(X + (size_t)n * 48);
#pragma unroll
    for (int i = 0; i < 12; ++i) {
        float4 u = xp[i];
        xr[i*4+0] = u.x; xr[i*4+1] = u.y; xr[i*4+2] = u.z; xr[i*4+3] = u.w;
    }
    float accp[32], accr[32];
#pragma unroll
    for (int j = 0; j < 32; ++j) { accp[j] = 0.f; accr[j] = 0.f; }
#pragma unroll
    for (int k = 0; k < 48; ++k) {
        float xk = xr[k];
#pragma unroll
        for (int j = 0; j < 32; ++j) {
            accp[j] += xk * sWl[k * 32 + j];
            accr[j] += xk * sWr[k * 32 + j];
        }
    }
    uint4* pp = reinterpret_cast<uint4*>(P + (size_t)n * 32);
    uint4* rp = reinterpret_cast<uint4*>(R + (size_t)n * 32);
#pragma unroll
    for (int i = 0; i < 4; ++i) {
        uint4 u, v;
        u.x = pack2(accp[i*8+0], accp[i*8+1]); u.y = pack2(accp[i*8+2], accp[i*8+3]);
        u.z = pack2(accp[i*8+4], accp[i*8+5]); u.w = pack2(accp[i*8+6], accp[i*8+7]);
        v.x = pack2(accr[i*8+0], accr[i*8+1]); v.y = pack2(accr[i*8+2], accr[i*8+3]);
        v.z = pack2(accr[i*8+4], accr[i*8+5]); v.w = pack2(accr[i*8+6], accr[i*8+7]);
        pp[i] = u;
        rp[i] = v;
    }
}

// ---- pass 1: coarse bucket sort of edges by dst>>8 --------------------------
__global__ __launch_bounds__(256) void bucket1_kernel(
    const int* __restrict__ ei, const int* __restrict__ flag,
    int* __restrict__ bsize, unsigned* __restrict__ bbuf)
{
    __shared__ int hist[NB], base[NB], cur[NB];
    for (int i = threadIdx.x; i < NB; i += 256) { hist[i] = 0; cur[i] = 0; }
    __syncthreads();
    int sh = *flag;
    int e0 = blockIdx.x * T1;
    int sreg[EPT], dreg[EPT];
#pragma unroll
    for (int it = 0; it < EPT; ++it) {
        int e = e0 + it * 256 + threadIdx.x;
        bool ok = e < NE;
        int s = ok ? edge_src(ei, e, sh) : -1;
        int d = ok ? edge_dst(ei, e, sh) : -1;
        if ((unsigned)s >= (unsigned)NN || (unsigned)d >= (unsigned)NN) { s = -1; d = -1; }
        sreg[it] = s; dreg[it] = d;
        if (d >= 0) atomicAdd(&hist[d >> 8], 1);
    }
    __syncthreads();
    for (int b = threadIdx.x; b < NB; b += 256) {
        int h = hist[b];
        base[b] = h ? atomicAdd(&bsize[b], h) : 0;
    }
    __syncthreads();
#pragma unroll
    for (int it = 0; it < EPT; ++it) {
        int s = sreg[it], d = dreg[it];
        if (d < 0) continue;
        int b = d >> 8;
        int pos = base[b] + atomicAdd(&cur[b], 1);
        if (pos < CAP)
            bbuf[(size_t)b * CAP + pos] = ((unsigned)s << 8) | (unsigned)(d & 255);
    }
}

// ---- bucket-start scan: 1 wave, 7 buckets/lane ------------------------------
__global__ void bscan_kernel(const int* __restrict__ bsize, int* __restrict__ bstart)
{
    int lane = threadIdx.x;     // 0..63
    int v[7], sum = 0;
#pragma unroll
    for (int j = 0; j < 7; ++j) {
        int b = lane * 7 + j;
        v[j] = (b < NB) ? min(bsize[b], CAP) : 0;
        sum += v[j];
    }
    int incl = wave_incl_scan(sum, lane);
    int excl = incl - sum;
#pragma unroll
    for (int j = 0; j < 7; ++j) {
        int b = lane * 7 + j;
        if (b < NB) bstart[b] = excl;
        excl += v[j];
    }
}

// ---- pass 2: per-bucket CSR fill, deg/rowstart emit (LDS atomics only) ------
__global__ __launch_bounds__(256) void bucket2_kernel(
    const int* __restrict__ bsize, const int* __restrict__ bstart,
    const unsigned* __restrict__ bbuf,
    int* __restrict__ deg, int* __restrict__ rowstart, int* __restrict__ csr_src)
{
    __shared__ int ldeg[256], lcur[256], ws[4];
    int b = blockIdx.x;
    int S  = min(bsize[b], CAP);
    int bs = bstart[b];
    const unsigned* bp = bbuf + (size_t)b * CAP;

    ldeg[threadIdx.x] = 0;
    __syncthreads();
    for (int i = threadIdx.x; i < S; i += 256)
        atomicAdd(&ldeg[bp[i] & 255u], 1);
    __syncthreads();

    int v = ldeg[threadIdx.x];
    int lane = threadIdx.x & 63, wid = threadIdx.x >> 6;
    int incl = wave_incl_scan(v, lane);
    if (lane == 63) ws[wid] = incl;
    __syncthreads();
    int off = 0;
#pragma unroll
    for (int w = 0; w < 3; ++w)
        if (wid > w) off += ws[w];
    int excl = off + incl - v;

    int node = (b << 8) + threadIdx.x;
    if (node < NN) {
        deg[node] = v;
        rowstart[node] = bs + excl;
    }
    lcur[threadIdx.x] = excl;
    __syncthreads();

    for (int i = threadIdx.x; i < S; i += 256) {
        unsigned pk = bp[i];
        int loc = pk & 255u;
        int pos = atomicAdd(&lcur[loc], 1);
        csr_src[bs + pos] = (int)(pk >> 8);
    }
}

// ---- layer1 gather + node update + fused layer-2 projections ---------------
// 4 lanes/node, 64 nodes/block. h exchanged through LDS (sh[k*64+loc]).
__global__ __launch_bounds__(256) void gather1f_kernel(
    const int* __restrict__ rowstart, const int* __restrict__ deg,
    const int* __restrict__ csr_src,
    const __hip_bfloat16* __restrict__ p1,     // [N,32] = x@W1l
    const __hip_bfloat16* __restrict__ r1,     // [N,32] = x@W1r
    const float* __restrict__ b1,              // [32]
    const float* __restrict__ W2l,             // [32,16]
    const float* __restrict__ W2r,             // [32,16]
    __hip_bfloat16* __restrict__ P2,           // [N,16]
    __hip_bfloat16* __restrict__ R2)           // [N,16]
{
    __shared__ float sW2l[32 * 16], sW2r[32 * 16], sb1[32];
    __shared__ float shh[32 * 64];             // h: [k][loc], 8 KB
    int t = threadIdx.x;
    for (int i = t; i < 32 * 16; i += 256) { sW2l[i] = W2l[i]; sW2r[i] = W2r[i]; }
    if (t < 32) sb1[t] = b1[t];
    __syncthreads();

    int loc = t >> 2, c = t & 3;
    int n = blockIdx.x * 64 + loc;
    bool valid = n < NN;

    if (valid) {
        int start = rowstart[n], dn = deg[n];
        float acc[8];
#pragma unroll
        for (int j = 0; j < 8; ++j) acc[j] = 0.f;
        const uint4* prow = reinterpret_cast<const uint4*>(p1);
        const int* cp = csr_src + start;
        int k = 0;
        for (; k + 2 <= dn; k += 2) {          // 2 independent gathers in flight
            int s0 = cp[k], s1 = cp[k + 1];
            uint4 a = prow[(size_t)s0 * 4 + c];
            uint4 b = prow[(size_t)s1 * 4 + c];
            acc[0] += bl(a.x) + bl(b.x); acc[1] += bh(a.x) + bh(b.x);
            acc[2] += bl(a.y) + bl(b.y); acc[3] += bh(a.y) + bh(b.y);
            acc[4] += bl(a.z) + bl(b.z); acc[5] += bh(a.z) + bh(b.z);
            acc[6] += bl(a.w) + bl(b.w); acc[7] += bh(a.w) + bh(b.w);
        }
        if (k < dn) {
            uint4 a = prow[(size_t)cp[k] * 4 + c];
            acc[0] += bl(a.x); acc[1] += bh(a.x);
            acc[2] += bl(a.y); acc[3] += bh(a.y);
            acc[4] += bl(a.z); acc[5] += bh(a.z);
            acc[6] += bl(a.w); acc[7] += bh(a.w);
        }
        float inv = 1.0f / fmaxf((float)dn, 1.0f);
        uint4 r = reinterpret_cast<const uint4*>(r1)[(size_t)n * 4 + c];
        float rr[8] = { bl(r.x), bh(r.x), bl(r.y), bh(r.y),
                        bl(r.z), bh(r.z), bl(r.w), bh(r.w) };
#pragma unroll
        for (int j = 0; j < 8; ++j) {
            float hv = fmaxf(acc[j] * inv + rr[j] + sb1[c * 8 + j], 0.f);
            shh[(c * 8 + j) * 64 + loc] = hv;
        }
    }
    __syncthreads();

    if (valid) {
        float accp[4], accr[4];
#pragma unroll
        for (int j = 0; j < 4; ++j) { accp[j] = 0.f; accr[j] = 0.f; }
#pragma unroll
        for (int k = 0; k < 32; ++k) {
            float hk = shh[k * 64 + loc];
#pragma unroll
            for (int j = 0; j < 4; ++j) {
                accp[j] += hk * sW2l[k * 16 + c * 4 + j];
                accr[j] += hk * sW2r[k * 16 + c * 4 + j];
            }
        }
        uint2 up, ur;
        up.x = pack2(accp[0], accp[1]); up.y = pack2(accp[2], accp[3]);
        ur.x = pack2(accr[0], accr[1]); ur.y = pack2(accr[2], accr[3]);
        reinterpret_cast<uint2*>(P2)[(size_t)n * 4 + c] = up;
        reinterpret_cast<uint2*>(R2)[(size_t)n * 4 + c] = ur;
    }
}

// ---- layer2 gather fused with final head: 2 lanes/node ---------------------
__global__ __launch_bounds__(256) void gather2_kernel(
    const int* __restrict__ rowstart, const int* __restrict__ deg,
    const int* __restrict__ csr_src,
    const __hip_bfloat16* __restrict__ P2,
    const __hip_bfloat16* __restrict__ R2,
    const float* __restrict__ b2,       // [16]
    const float* __restrict__ Wlin,     // [16,2]
    const float* __restrict__ blin,     // [2]
    float* __restrict__ out)            // [NN,2]
{
    __shared__ float sb[16], sW[32], sbl[2];
    if (threadIdx.x < 16) sb[threadIdx.x] = b2[threadIdx.x];
    else if (threadIdx.x < 48) sW[threadIdx.x - 16] = Wlin[threadIdx.x - 16];
    else if (threadIdx.x < 50) sbl[threadIdx.x - 48] = blin[threadIdx.x - 48];
    __syncthreads();
    int t = blockIdx.x * 256 + threadIdx.x;
    int n = t >> 1, c = t & 1;
    if (n >= NN) return;
    int start = rowstart[n], dn = deg[n];

    float acc[8];
#pragma unroll
    for (int j = 0; j < 8; ++j) acc[j] = 0.f;
    const uint4* prow = reinterpret_cast<const uint4*>(P2);
    const int* cp = csr_src + start;
    int k = 0;
    for (; k + 2 <= dn; k += 2) {
        int s0 = cp[k], s1 = cp[k + 1];
        uint4 a = prow[(size_t)s0 * 2 + c];
        uint4 b = prow[(size_t)s1 * 2 + c];
        acc[0] += bl(a.x) + bl(b.x); acc[1] += bh(a.x) + bh(b.x);
        acc[2] += bl(a.y) + bl(b.y); acc[3] += bh(a.y) + bh(b.y);
        acc[4] += bl(a.z) + bl(b.z); acc[5] += bh(a.z) + bh(b.z);
        acc[6] += bl(a.w) + bl(b.w); acc[7] += bh(a.w) + bh(b.w);
    }
    if (k < dn) {
        uint4 a = prow[(size_t)cp[k] * 2 + c];
        acc[0] += bl(a.x); acc[1] += bh(a.x);
        acc[2] += bl(a.y); acc[3] += bh(a.y);
        acc[4] += bl(a.z); acc[5] += bh(a.z);
        acc[6] += bl(a.w); acc[7] += bh(a.w);
    }
    float inv = 1.0f / fmaxf((float)dn, 1.0f);
    uint4 r = reinterpret_cast<const uint4*>(R2)[(size_t)n * 2 + c];
    float rr[8] = { bl(r.x), bh(r.x), bl(r.y), bh(r.y),
                    bl(r.z), bh(r.z), bl(r.w), bh(r.w) };
    float o0 = 0.f, o1 = 0.f;
#pragma unroll
    for (int j = 0; j < 8; ++j) {
        int kk = c * 8 + j;
        float hv = fmaxf(acc[j] * inv + rr[j] + sb[kk], 0.f);
        o0 += hv * sW[kk * 2];
        o1 += hv * sW[kk * 2 + 1];
    }
    o0 += __shfl_xor(o0, 1, 64);
    o1 += __shfl_xor(o1, 1, 64);
    if (c == 0)
        reinterpret_cast<float2*>(out)[n] = make_float2(o0 + sbl[0], o1 + sbl[1]);
}

extern "C" void kernel_launch(void* const* d_in, const int* in_sizes, int n_in,
                              void* d_out, int out_size, void* d_ws, size_t ws_size,
                              hipStream_t stream)
{
    const float* x    = (const float*)d_in[0];
    const int*   ei   = (const int*)d_in[1];
    const float* W1l  = (const float*)d_in[2];
    const float* W1r  = (const float*)d_in[3];
    const float* b1   = (const float*)d_in[4];
    const float* W2l  = (const float*)d_in[5];
    const float* W2r  = (const float*)d_in[6];
    const float* b2   = (const float*)d_in[7];
    const float* Wlin = (const float*)d_in[8];
    const float* blin = (const float*)d_in[9];
    float* out = (float*)d_out;

    // ---- workspace layout (bytes; ws_size = 256 MiB per harness fill) ----
    char* wsb = (char*)d_ws;
    int*      flag     = (int*)(wsb);                       // @0
    int*      bsize    = (int*)(wsb + 64);                  // int[NB]
    int*      bstart   = (int*)(wsb + 2048);                // int[NB]
    int*      deg      = (int*)(wsb + 4096);                // int[N]
    int*      rowstart = (int*)(wsb + 404096);              // int[N]
    int*      csr_src  = (int*)(wsb + 804096);              // int[E]   6.4 MB
    unsigned* bbuf     = (unsigned*)(wsb + 7204096);        // u32[NB*CAP] 7.2 MB
    __hip_bfloat16* p1 = (__hip_bfloat16*)(wsb + 14412032); // bf16[N,32] 6.4 MB
    __hip_bfloat16* r1 = (__hip_bfloat16*)(wsb + 20812032); // bf16[N,32] 6.4 MB
    __hip_bfloat16* p2 = (__hip_bfloat16*)(wsb + 27212032); // bf16[N,16] 3.2 MB
    __hip_bfloat16* r2 = (__hip_bfloat16*)(wsb + 30412032); // bf16[N,16] 3.2 MB

    dim3 blk(256);

    hipMemsetAsync(bsize, 0, NB * sizeof(int), stream);
    detect_kernel<<<1, blk, 0, stream>>>(ei, flag);

    lin2_kernel<<<NCH, blk, 0, stream>>>(x, W1l, W1r, p1, r1);
    bucket1_kernel<<<(NE + T1 - 1) / T1, blk, 0, stream>>>(ei, flag, bsize, bbuf);
    bscan_kernel<<<1, 64, 0, stream>>>(bsize, bstart);
    bucket2_kernel<<<NB, blk, 0, stream>>>(bsize, bstart, bbuf, deg, rowstart, csr_src);

    gather1f_kernel<<<(NN + 63) / 64, blk, 0, stream>>>(
        rowstart, deg, csr_src, p1, r1, b1, W2l, W2r, p2, r2);
    gather2_kernel<<<(NN * 2 + 255) / 256, blk, 0, stream>>>(
        rowstart, deg, csr_src, p2, r2, b2, Wlin, blin, out);
}

// Round 9
// 187.697 us; speedup vs baseline: 3.6045x; 1.1519x over previous
//
#include <hip/hip_runtime.h>
#include <hip/hip_bf16.h>

// FraudGNN: 2-layer GraphSAGE (mean aggr) + linear head.
// N=100000, E=1600000, feat 48 -> 32 -> 16 -> 2. fp32 in/out, int edge_index.
//
// R9 = R8 with the CSR-overflow bug fixed:
//  R8 reserved prefix space per bucket from (bsize+3)&~3 but consumed
//  sum((deg+3)&~3) <= bsize + 768 -> segments overflowed into the next
//  bucket (concurrent clobber). Fix: fixed per-bucket region SEG = CAP+768
//  ints (worst case), bs = b*SEG. No prefix needed at all; holes unread.
//
//  K1 = lin2 || bucket1 (block-ranged fusion, in-block int64 detect)
//  K2 = per-bucket CSR fill, x4-padded node segments (pad src = NN zero row)
//  K3 = gather1: 4 lanes/node, tail-free unroll-4, fused update + layer-2 proj
//  K4 = gather2: 2 lanes/node, unroll-4, fused final head
// Algebra: mean(x[src])@Wl == segsum((x@Wl)[src])/cnt -> project first,
// aggregate 32/16-wide bf16 rows by gather (zero float atomics).

constexpr int NN  = 100000;
constexpr int NE  = 1600000;
constexpr int NCH = (NN + 255) / 256;   // 391 node chunks (lin2 blocks)
constexpr int NB  = 391;                // buckets = dst >> 8
constexpr int CAP = 4608;               // per-bucket capacity (mean 4092, +8 sigma)
constexpr int SEG = CAP + 3 * 256;      // 5376: worst-case padded bucket footprint
constexpr int T1  = 2048;               // edges per bucket1 block
constexpr int EPT = T1 / 256;           // 8 edges cached per thread
constexpr int NB1 = (NE + T1 - 1) / T1; // 782 bucket1 blocks

__device__ __forceinline__ float bl(unsigned u) { return __uint_as_float(u << 16); }
__device__ __forceinline__ float bh(unsigned u) { return __uint_as_float(u & 0xffff0000u); }
__device__ __forceinline__ unsigned f2b(float x) {
    unsigned u = __float_as_uint(x);
    return (u + 0x7fffu + ((u >> 16) & 1u)) >> 16;
}
__device__ __forceinline__ unsigned pack2(float a, float b) {
    return f2b(a) | (f2b(b) << 16);
}

__device__ __forceinline__ int wave_incl_scan(int v, int lane) {
#pragma unroll
    for (int d = 1; d < 64; d <<= 1) {
        int t = __shfl_up(v, d, 64);
        if (lane >= d) v += t;
    }
    return v;
}

// ---- K1: lin2 (blocks [0,NCH)) || bucket1 (blocks [NCH, NCH+NB1)) ----------
__global__ __launch_bounds__(256) void k1_kernel(
    const float* __restrict__ X,
    const float* __restrict__ Wl,
    const float* __restrict__ Wr,
    const int*   __restrict__ ei,
    int* __restrict__ bsize, unsigned* __restrict__ bbuf,
    __hip_bfloat16* __restrict__ P, __hip_bfloat16* __restrict__ R)
{
    __shared__ float sW[2][48 * 32];            // 12 KB (lin part)
    __shared__ int hist[NB], base[NB], cur[NB]; // 4.7 KB (bucket part)
    __shared__ int s_any;

    if (blockIdx.x < NCH) {
        // ---------------- lin2: P = X@Wl, R = X@Wr, + zero row at NN --------
        for (int i = threadIdx.x; i < 48 * 32; i += 256) {
            sW[0][i] = Wl[i];
            sW[1][i] = Wr[i];
        }
        __syncthreads();
        int n = blockIdx.x * 256 + threadIdx.x;
        if (n > NN) return;
        if (n == NN) {                           // zero row (CSR pad target)
            uint4 z = make_uint4(0, 0, 0, 0);
            uint4* pp = reinterpret_cast<uint4*>(P + (size_t)NN * 32);
#pragma unroll
            for (int i = 0; i < 4; ++i) pp[i] = z;
            return;
        }
        float xr[48];
        const float4* xp = reinterpret_cast<const float4*>(X + (size_t)n * 48);
#pragma unroll
        for (int i = 0; i < 12; ++i) {
            float4 u = xp[i];
            xr[i*4+0] = u.x; xr[i*4+1] = u.y; xr[i*4+2] = u.z; xr[i*4+3] = u.w;
        }
        float accp[32], accr[32];
#pragma unroll
        for (int j = 0; j < 32; ++j) { accp[j] = 0.f; accr[j] = 0.f; }
#pragma unroll
        for (int k = 0; k < 48; ++k) {
            float xk = xr[k];
#pragma unroll
            for (int j = 0; j < 32; ++j) {
                accp[j] += xk * sW[0][k * 32 + j];
                accr[j] += xk * sW[1][k * 32 + j];
            }
        }
        uint4* pp = reinterpret_cast<uint4*>(P + (size_t)n * 32);
        uint4* rp = reinterpret_cast<uint4*>(R + (size_t)n * 32);
#pragma unroll
        for (int i = 0; i < 4; ++i) {
            uint4 u, v;
            u.x = pack2(accp[i*8+0], accp[i*8+1]); u.y = pack2(accp[i*8+2], accp[i*8+3]);
            u.z = pack2(accp[i*8+4], accp[i*8+5]); u.w = pack2(accp[i*8+6], accp[i*8+7]);
            v.x = pack2(accr[i*8+0], accr[i*8+1]); v.y = pack2(accr[i*8+2], accr[i*8+3]);
            v.z = pack2(accr[i*8+4], accr[i*8+5]); v.w = pack2(accr[i*8+6], accr[i*8+7]);
            pp[i] = u;
            rp[i] = v;
        }
    } else {
        // ---------------- bucket1: coarse sort edges by dst>>8 --------------
        if (threadIdx.x == 0) s_any = 0;
        for (int i = threadIdx.x; i < NB; i += 256) { hist[i] = 0; cur[i] = 0; }
        __syncthreads();
        // self-detect edge_index layout: int64 -> odd words all zero
        int dv = 0;
        for (int i = threadIdx.x; i < 2048; i += 256) dv |= ei[2 * i + 1];
        if (dv != 0) atomicOr(&s_any, 1);
        __syncthreads();
        int sh = (s_any == 0) ? 1 : 0;

        int e0 = (blockIdx.x - NCH) * T1;
        int sreg[EPT], dreg[EPT];
#pragma unroll
        for (int it = 0; it < EPT; ++it) {
            int e = e0 + it * 256 + threadIdx.x;
            bool ok = e < NE;
            int s = ok ? ei[(size_t)e << sh] : -1;
            int d = ok ? ei[(size_t)(NE + e) << sh] : -1;
            if ((unsigned)s >= (unsigned)NN || (unsigned)d >= (unsigned)NN) { s = -1; d = -1; }
            sreg[it] = s; dreg[it] = d;
            if (d >= 0) atomicAdd(&hist[d >> 8], 1);
        }
        __syncthreads();
        for (int b = threadIdx.x; b < NB; b += 256) {
            int h = hist[b];
            base[b] = h ? atomicAdd(&bsize[b], h) : 0;
        }
        __syncthreads();
#pragma unroll
        for (int it = 0; it < EPT; ++it) {
            int s = sreg[it], d = dreg[it];
            if (d < 0) continue;
            int b = d >> 8;
            int pos = base[b] + atomicAdd(&cur[b], 1);
            if (pos < CAP)
                bbuf[(size_t)b * CAP + pos] = ((unsigned)s << 8) | (unsigned)(d & 255);
        }
    }
}

// ---- K2: per-bucket CSR fill into fixed region b*SEG, x4-padded segments ----
__global__ __launch_bounds__(256) void k2_kernel(
    const int* __restrict__ bsize, const unsigned* __restrict__ bbuf,
    int* __restrict__ deg, int* __restrict__ rowstart, int* __restrict__ csr_src)
{
    __shared__ int ldeg[256], lcur[256], ws[4];
    int b = blockIdx.x, t = threadIdx.x;
    int bs = b * SEG;                       // fixed region: no cross-bucket coupling

    int S = min(bsize[b], CAP);
    const unsigned* bp = bbuf + (size_t)b * CAP;
    ldeg[t] = 0;
    __syncthreads();
    for (int i = t; i < S; i += 256)
        atomicAdd(&ldeg[bp[i] & 255u], 1);
    __syncthreads();

    int v  = ldeg[t];
    int pv = (v + 3) & ~3;                  // padded per-node length
    int lane = t & 63, wid = t >> 6;
    int incl = wave_incl_scan(pv, lane);
    if (lane == 63) ws[wid] = incl;
    __syncthreads();
    int off = 0;
#pragma unroll
    for (int w = 0; w < 3; ++w)
        if (wid > w) off += ws[w];
    int excl = off + incl - pv;             // <= S + 3*256 - pv <= SEG - pv

    int node = (b << 8) + t;
    if (node < NN) {
        deg[node] = v;
        rowstart[node] = bs + excl;         // 4-aligned (bs, excl both x4)
    }
    lcur[t] = excl;
    __syncthreads();

    for (int i = t; i < S; i += 256) {
        unsigned pk = bp[i];
        int pos = atomicAdd(&lcur[pk & 255u], 1);
        csr_src[bs + pos] = (int)(pk >> 8);
    }
    // pad tail of own node's segment with zero-row id (disjoint from fills)
    for (int p = excl + v; p < excl + pv; ++p)
        csr_src[bs + p] = NN;
}

// ---- K3: layer1 gather (unroll-4, int4 idx) + update + layer2 projections ---
__global__ __launch_bounds__(256) void gather1f_kernel(
    const int* __restrict__ rowstart, const int* __restrict__ deg,
    const int* __restrict__ csr_src,
    const __hip_bfloat16* __restrict__ p1,     // [N+1,32] (row NN = 0)
    const __hip_bfloat16* __restrict__ r1,     // [N,32]
    const float* __restrict__ b1,              // [32]
    const float* __restrict__ W2l,             // [32,16]
    const float* __restrict__ W2r,             // [32,16]
    __hip_bfloat16* __restrict__ P2,           // [N+1,16] (row NN = 0)
    __hip_bfloat16* __restrict__ R2)           // [N+1,16]
{
    __shared__ float sW2l[32 * 16], sW2r[32 * 16], sb1[32];
    __shared__ float shh[32 * 64];             // h exchange, 8 KB
    int t = threadIdx.x;
    for (int i = t; i < 32 * 16; i += 256) { sW2l[i] = W2l[i]; sW2r[i] = W2r[i]; }
    if (t < 32) sb1[t] = b1[t];
    __syncthreads();

    int loc = t >> 2, c = t & 3;
    int n = blockIdx.x * 64 + loc;
    bool valid = n < NN;

    if (valid) {
        int start = rowstart[n], dn = deg[n];
        int pv4 = ((dn + 3) & ~3) >> 2;
        float acc[8];
#pragma unroll
        for (int j = 0; j < 8; ++j) acc[j] = 0.f;
        const uint4* prow = reinterpret_cast<const uint4*>(p1);
        const int4* cp4 = reinterpret_cast<const int4*>(csr_src + start);
        for (int k = 0; k < pv4; ++k) {         // 4 row fetches in flight
            int4 s4 = cp4[k];
            uint4 a = prow[(size_t)s4.x * 4 + c];
            uint4 b = prow[(size_t)s4.y * 4 + c];
            uint4 d = prow[(size_t)s4.z * 4 + c];
            uint4 e = prow[(size_t)s4.w * 4 + c];
            acc[0] += bl(a.x) + bl(b.x) + bl(d.x) + bl(e.x);
            acc[1] += bh(a.x) + bh(b.x) + bh(d.x) + bh(e.x);
            acc[2] += bl(a.y) + bl(b.y) + bl(d.y) + bl(e.y);
            acc[3] += bh(a.y) + bh(b.y) + bh(d.y) + bh(e.y);
            acc[4] += bl(a.z) + bl(b.z) + bl(d.z) + bl(e.z);
            acc[5] += bh(a.z) + bh(b.z) + bh(d.z) + bh(e.z);
            acc[6] += bl(a.w) + bl(b.w) + bl(d.w) + bl(e.w);
            acc[7] += bh(a.w) + bh(b.w) + bh(d.w) + bh(e.w);
        }
        float inv = 1.0f / fmaxf((float)dn, 1.0f);
        uint4 r = reinterpret_cast<const uint4*>(r1)[(size_t)n * 4 + c];
        float rr[8] = { bl(r.x), bh(r.x), bl(r.y), bh(r.y),
                        bl(r.z), bh(r.z), bl(r.w), bh(r.w) };
#pragma unroll
        for (int j = 0; j < 8; ++j)
            shh[(c * 8 + j) * 64 + loc] = fmaxf(acc[j] * inv + rr[j] + sb1[c * 8 + j], 0.f);
    }
    __syncthreads();

    if (valid) {
        float accp[4], accr[4];
#pragma unroll
        for (int j = 0; j < 4; ++j) { accp[j] = 0.f; accr[j] = 0.f; }
#pragma unroll
        for (int k = 0; k < 32; ++k) {
            float hk = shh[k * 64 + loc];
#pragma unroll
            for (int j = 0; j < 4; ++j) {
                accp[j] += hk * sW2l[k * 16 + c * 4 + j];
                accr[j] += hk * sW2r[k * 16 + c * 4 + j];
            }
        }
        uint2 up, ur;
        up.x = pack2(accp[0], accp[1]); up.y = pack2(accp[2], accp[3]);
        ur.x = pack2(accr[0], accr[1]); ur.y = pack2(accr[2], accr[3]);
        reinterpret_cast<uint2*>(P2)[(size_t)n * 4 + c] = up;
        reinterpret_cast<uint2*>(R2)[(size_t)n * 4 + c] = ur;
    } else if (n == NN) {                       // zero row for layer-2 pads
        uint2 z = make_uint2(0, 0);
        reinterpret_cast<uint2*>(P2)[(size_t)NN * 4 + c] = z;
        reinterpret_cast<uint2*>(R2)[(size_t)NN * 4 + c] = z;
    }
}

// ---- K4: layer2 gather (unroll-4) fused with final head ---------------------
__global__ __launch_bounds__(256) void gather2_kernel(
    const int* __restrict__ rowstart, const int* __restrict__ deg,
    const int* __restrict__ csr_src,
    const __hip_bfloat16* __restrict__ P2,
    const __hip_bfloat16* __restrict__ R2,
    const float* __restrict__ b2,       // [16]
    const float* __restrict__ Wlin,     // [16,2]
    const float* __restrict__ blin,     // [2]
    float* __restrict__ out)            // [NN,2]
{
    __shared__ float sb[16], sW[32], sbl[2];
    if (threadIdx.x < 16) sb[threadIdx.x] = b2[threadIdx.x];
    else if (threadIdx.x < 48) sW[threadIdx.x - 16] = Wlin[threadIdx.x - 16];
    else if (threadIdx.x < 50) sbl[threadIdx.x - 48] = blin[threadIdx.x - 48];
    __syncthreads();
    int t = blockIdx.x * 256 + threadIdx.x;
    int n = t >> 1, c = t & 1;
    if (n >= NN) return;
    int start = rowstart[n], dn = deg[n];
    int pv4 = ((dn + 3) & ~3) >> 2;

    float acc[8];
#pragma unroll
    for (int j = 0; j < 8; ++j) acc[j] = 0.f;
    const uint4* prow = reinterpret_cast<const uint4*>(P2);
    const int4* cp4 = reinterpret_cast<const int4*>(csr_src + start);
    for (int k = 0; k < pv4; ++k) {
        int4 s4 = cp4[k];
        uint4 a = prow[(size_t)s4.x * 2 + c];
        uint4 b = prow[(size_t)s4.y * 2 + c];
        uint4 d = prow[(size_t)s4.z * 2 + c];
        uint4 e = prow[(size_t)s4.w * 2 + c];
        acc[0] += bl(a.x) + bl(b.x) + bl(d.x) + bl(e.x);
        acc[1] += bh(a.x) + bh(b.x) + bh(d.x) + bh(e.x);
        acc[2] += bl(a.y) + bl(b.y) + bl(d.y) + bl(e.y);
        acc[3] += bh(a.y) + bh(b.y) + bh(d.y) + bh(e.y);
        acc[4] += bl(a.z) + bl(b.z) + bl(d.z) + bl(e.z);
        acc[5] += bh(a.z) + bh(b.z) + bh(d.z) + bh(e.z);
        acc[6] += bl(a.w) + bl(b.w) + bl(d.w) + bl(e.w);
        acc[7] += bh(a.w) + bh(b.w) + bh(d.w) + bh(e.w);
    }
    float inv = 1.0f / fmaxf((float)dn, 1.0f);
    uint4 r = reinterpret_cast<const uint4*>(R2)[(size_t)n * 2 + c];
    float rr[8] = { bl(r.x), bh(r.x), bl(r.y), bh(r.y),
                    bl(r.z), bh(r.z), bl(r.w), bh(r.w) };
    float o0 = 0.f, o1 = 0.f;
#pragma unroll
    for (int j = 0; j < 8; ++j) {
        int kk = c * 8 + j;
        float hv = fmaxf(acc[j] * inv + rr[j] + sb[kk], 0.f);
        o0 += hv * sW[kk * 2];
        o1 += hv * sW[kk * 2 + 1];
    }
    o0 += __shfl_xor(o0, 1, 64);
    o1 += __shfl_xor(o1, 1, 64);
    if (c == 0)
        reinterpret_cast<float2*>(out)[n] = make_float2(o0 + sbl[0], o1 + sbl[1]);
}

extern "C" void kernel_launch(void* const* d_in, const int* in_sizes, int n_in,
                              void* d_out, int out_size, void* d_ws, size_t ws_size,
                              hipStream_t stream)
{
    const float* x    = (const float*)d_in[0];
    const int*   ei   = (const int*)d_in[1];
    const float* W1l  = (const float*)d_in[2];
    const float* W1r  = (const float*)d_in[3];
    const float* b1   = (const float*)d_in[4];
    const float* W2l  = (const float*)d_in[5];
    const float* W2r  = (const float*)d_in[6];
    const float* b2   = (const float*)d_in[7];
    const float* Wlin = (const float*)d_in[8];
    const float* blin = (const float*)d_in[9];
    float* out = (float*)d_out;

    // ---- workspace layout (bytes; ws_size = 256 MiB) ----
    char* wsb = (char*)d_ws;
    int*      bsize    = (int*)(wsb + 64);              // int[NB]
    int*      deg      = (int*)(wsb + 4096);            // int[N]
    int*      rowstart = (int*)(wsb + 404096);          // int[N]
    int*      csr_src  = (int*)(wsb + 804096);          // int[NB*SEG] 8.41 MB
    unsigned* bbuf     = (unsigned*)(wsb + 9300000);    // u32[NB*CAP] 7.21 MB
    __hip_bfloat16* p1 = (__hip_bfloat16*)(wsb + 16600000); // bf16[N+1,32]
    __hip_bfloat16* r1 = (__hip_bfloat16*)(wsb + 23100000); // bf16[N,32]
    __hip_bfloat16* p2 = (__hip_bfloat16*)(wsb + 29600000); // bf16[N+1,16]
    __hip_bfloat16* r2 = (__hip_bfloat16*)(wsb + 32900000); // bf16[N+1,16]

    dim3 blk(256);

    hipMemsetAsync(bsize, 0, NB * sizeof(int), stream);
    k1_kernel<<<NCH + NB1, blk, 0, stream>>>(x, W1l, W1r, ei, bsize, bbuf, p1, r1);
    k2_kernel<<<NB, blk, 0, stream>>>(bsize, bbuf, deg, rowstart, csr_src);
    gather1f_kernel<<<(NN + 1 + 63) / 64, blk, 0, stream>>>(
        rowstart, deg, csr_src, p1, r1, b1, W2l, W2r, p2, r2);
    gather2_kernel<<<(NN * 2 + 255) / 256, blk, 0, stream>>>(
        rowstart, deg, csr_src, p2, r2, b2, Wlin, blin, out);
}